// Round 3
// baseline (96.891 us; speedup 1.0000x reference)
//
#include <hip/hip_runtime.h>

// RankingLoss: loss = (1/N) * sum_i [ cnt_i>0 ? (sum_{j: t[j]<t[i]} max(0, m - (p[i]-p[j]))) / cnt_i : 0 ]
// N=16384, margin=0.1, fp32 in/out.
//
// Single fused kernel: R rows per block, float4 j-loads shared across rows,
// ballot-based count (scalar pipe), per-block atomicAdd of sum_r(per_row)/N
// into d_out[0] (zeroed by hipMemsetAsync). ~6 VALU/pair floor:
// v_cmp, v_add, v_max, v_cndmask, v_add.

constexpr float MARGIN = 0.1f;
constexpr int R = 8;      // rows per block
constexpr int T = 256;    // threads per block

__global__ __launch_bounds__(T) void rank_rows(const float* __restrict__ pred,
                                               const float* __restrict__ target,
                                               float* __restrict__ out,
                                               int n, float inv_n) {
    const int base = blockIdx.x * R;

    float ti[R], ci[R];
    #pragma unroll
    for (int r = 0; r < R; ++r) {
        ti[r] = target[base + r];
        ci[r] = MARGIN - pred[base + r];
    }

    float sum[R];
    unsigned int cnt[R];   // wave-uniform (ballot-counted) -> SGPRs
    #pragma unroll
    for (int r = 0; r < R; ++r) { sum[r] = 0.f; cnt[r] = 0u; }

    const float4* __restrict__ t4 = (const float4*)target;
    const float4* __restrict__ p4 = (const float4*)pred;
    const int n4 = n >> 2;   // 4096, exact multiple of T/..., no tail lanes

    #pragma unroll 4
    for (int j = (int)threadIdx.x; j < n4; j += T) {
        const float4 tj = t4[j];
        const float4 pj = p4[j];
        #pragma unroll
        for (int r = 0; r < R; ++r) {
            const float tir = ti[r], cir = ci[r];
            {
                const bool m = tj.x < tir;
                const float h = fmaxf(0.f, cir + pj.x);
                sum[r] += m ? h : 0.f;
                cnt[r] += (unsigned)__popcll(__ballot(m));
            }
            {
                const bool m = tj.y < tir;
                const float h = fmaxf(0.f, cir + pj.y);
                sum[r] += m ? h : 0.f;
                cnt[r] += (unsigned)__popcll(__ballot(m));
            }
            {
                const bool m = tj.z < tir;
                const float h = fmaxf(0.f, cir + pj.z);
                sum[r] += m ? h : 0.f;
                cnt[r] += (unsigned)__popcll(__ballot(m));
            }
            {
                const bool m = tj.w < tir;
                const float h = fmaxf(0.f, cir + pj.w);
                sum[r] += m ? h : 0.f;
                cnt[r] += (unsigned)__popcll(__ballot(m));
            }
        }
    }

    // Per-row: sums need cross-lane reduce; counts are already wave-uniform.
    __shared__ float        ls[T / 64][R];
    __shared__ unsigned int lc[T / 64][R];
    __shared__ float        row_val[R];
    const int lane = threadIdx.x & 63;
    const int wv   = threadIdx.x >> 6;

    #pragma unroll
    for (int r = 0; r < R; ++r) {
        float s = sum[r];
        #pragma unroll
        for (int off = 32; off > 0; off >>= 1) s += __shfl_down(s, off, 64);
        if (lane == 0) { ls[wv][r] = s; lc[wv][r] = cnt[r]; }
    }
    __syncthreads();

    if ((int)threadIdx.x < R) {
        float s = 0.f;
        unsigned int c = 0u;
        #pragma unroll
        for (int w = 0; w < T / 64; ++w) { s += ls[w][threadIdx.x]; c += lc[w][threadIdx.x]; }
        row_val[threadIdx.x] = (c > 0u) ? (s / (float)c) : 0.f;
    }
    __syncthreads();

    if (threadIdx.x == 0) {
        float local = 0.f;
        #pragma unroll
        for (int r = 0; r < R; ++r) local += row_val[r];
        atomicAdd(out, local * inv_n);
    }
}

extern "C" void kernel_launch(void* const* d_in, const int* in_sizes, int n_in,
                              void* d_out, int out_size, void* d_ws, size_t ws_size,
                              hipStream_t stream) {
    const float* pred   = (const float*)d_in[0];
    const float* target = (const float*)d_in[1];
    const int n = in_sizes[0];                 // 16384

    float* out = (float*)d_out;
    hipMemsetAsync(out, 0, sizeof(float) * (size_t)out_size, stream);

    rank_rows<<<n / R, T, 0, stream>>>(pred, target, out, n, 1.0f / (float)n);
}